// Round 3
// baseline (1310.588 us; speedup 1.0000x reference)
//
#include <hip/hip_runtime.h>
#include <math.h>

#define H 511
#define L 2048
#define NST 32
#define NLAYERS 4
#define LN_EPS 1e-5f

// ---------------------------------------------------------------------------
// Precompute per-(h,n): w = exp(dt*A)  and  c = 2 * (C_re + i C_im) * (w-1)/A
// ---------------------------------------------------------------------------
__global__ __launch_bounds__(256) void precompute_coef(
    const float* __restrict__ log_dt,
    const float* __restrict__ A_real_log,
    const float* __restrict__ A_imag,
    const float* __restrict__ C_re,
    const float* __restrict__ C_im,
    float* __restrict__ wr_o, float* __restrict__ wi_o,
    float* __restrict__ cr_o, float* __restrict__ ci_o)
{
    int idx = blockIdx.x * blockDim.x + threadIdx.x;
    if (idx >= H * NST) return;
    int h = idx / NST;
    float Ar = -expf(A_real_log[idx]);
    float Ai = A_imag[idx];
    float dt = expf(log_dt[h]);
    float dr = Ar * dt, di = Ai * dt;
    float er = expf(dr);
    float wr = er * cosf(di);
    float wi = er * sinf(di);
    // q = (w - 1) / A   (complex divide)
    float den = Ar * Ar + Ai * Ai;
    float a = wr - 1.0f, b = wi;
    float inv = 1.0f / den;
    float qr = (a * Ar + b * Ai) * inv;
    float qi = (b * Ar - a * Ai) * inv;
    // c = 2 * (C_re + i C_im) * q
    float crv = 2.0f * (C_re[idx] * qr - C_im[idx] * qi);
    float civ = 2.0f * (C_re[idx] * qi + C_im[idx] * qr);
    wr_o[idx] = wr; wi_o[idx] = wi; cr_o[idx] = crv; ci_o[idx] = civ;
}

// ---------------------------------------------------------------------------
// DPP helpers: sum across each 32-lane half; result lands in lanes 31 and 63.
// ---------------------------------------------------------------------------
template <int CTRL, int ROW_MASK>
__device__ __forceinline__ float dpp_add(float x) {
    int r = __builtin_amdgcn_update_dpp(0, __float_as_int(x), CTRL, ROW_MASK, 0xf, true);
    return x + __int_as_float(r);
}
__device__ __forceinline__ float reduce32_to_lane31(float p) {
    p = dpp_add<0x111, 0xf>(p);  // row_shr:1
    p = dpp_add<0x112, 0xf>(p);  // row_shr:2
    p = dpp_add<0x114, 0xf>(p);  // row_shr:4
    p = dpp_add<0x118, 0xf>(p);  // row_shr:8
    p = dpp_add<0x142, 0xa>(p);  // row_bcast:15 into rows 1,3
    return p;                    // lane31 = sum(lanes 0..31), lane63 = sum(32..63)
}

__device__ __forceinline__ float gelu_tanh(float v) {
    const float c0 = 0.7978845608028654f;  // sqrt(2/pi)
    float t = tanhf(c0 * (v + 0.044715f * v * v * v));
    return 0.5f * v * (1.0f + t);
}

// ---------------------------------------------------------------------------
// Causal S4D conv via state recurrence + D skip + gelu.
// One 64-thread wave handles 2 channels (32 lanes each; lane = state index n).
// ---------------------------------------------------------------------------
__global__ __launch_bounds__(64) void conv_kernel(
    const float* __restrict__ z,       // (H,L)
    const float* __restrict__ wr_,
    const float* __restrict__ wi_,
    const float* __restrict__ cr_,
    const float* __restrict__ ci_,
    const float* __restrict__ D_skip,  // (H)
    float* __restrict__ y)             // (H,L) gelu output
{
    __shared__ float zs[2][L];
    __shared__ float ys[2][L];
    const int half = threadIdx.x >> 5;
    const int lane = threadIdx.x & 31;
    const int h = blockIdx.x * 2 + half;
    const int hh = (h < H) ? h : (H - 1);

    const float* zrow = z + (size_t)hh * L;
    for (int i = lane; i < L; i += 32) zs[half][i] = zrow[i];

    const int cidx = hh * NST + lane;
    const float wr = wr_[cidx], wi = wi_[cidx];
    const float cr = cr_[cidx], ci = ci_[cidx];
    const float Dh = D_skip[hh];
    __syncthreads();

    float sr = 0.0f, si = 0.0f;
    for (int l = 0; l < L; ++l) {
        float zl = zs[half][l];
        float nsr = fmaf(wr, sr, fmaf(-wi, si, zl));
        float nsi = fmaf(wr, si, wi * sr);
        sr = nsr; si = nsi;
        float p = fmaf(cr, sr, -ci * si);
        p = reduce32_to_lane31(p);
        if (lane == 31) ys[half][l] = fmaf(Dh, zl, p);
    }
    __syncthreads();

    if (h < H) {
        float* yrow = y + (size_t)h * L;
        for (int i = lane; i < L; i += 32) yrow[i] = gelu_tanh(ys[half][i]);
    }
}

// ---------------------------------------------------------------------------
// Fused: y2 = glu_w @ y + glu_b ; out = y2[:H]*sigmoid(y2[H:]) + residual
// Tiled fp32: BM=32 rows of H (both gate rows h and h+H), BN=64 cols, BK=16.
// 256 threads; each thread: 2 rows x 4 cols x 2 gates.
// ---------------------------------------------------------------------------
#define BM 32
#define BN 64
#define BK 16
__global__ __launch_bounds__(256) void glu_matmul(
    const float* __restrict__ y,     // (H,L)
    const float* __restrict__ W,     // (2H,H)
    const float* __restrict__ bias,  // (2H)
    const float* __restrict__ zres,  // (H,L) residual
    float* __restrict__ out)         // (H,L)
{
    __shared__ __align__(16) float Ws1[BK][BM];
    __shared__ __align__(16) float Ws2[BK][BM];
    __shared__ __align__(16) float Ys[BK][BN];

    const int tid = threadIdx.x;
    const int h0 = blockIdx.y * BM;
    const int l0 = blockIdx.x * BN;
    const int tx = tid & 15;   // col group -> cols l0 + tx*4 .. +3
    const int ty = tid >> 4;   // row group -> rows h0 + ty*2, +1

    float acc1[2][4] = {{0.f,0.f,0.f,0.f},{0.f,0.f,0.f,0.f}};
    float acc2[2][4] = {{0.f,0.f,0.f,0.f},{0.f,0.f,0.f,0.f}};

    for (int k0 = 0; k0 < H; k0 += BK) {
        // Stage W tiles (32 rows x 16 k, both gates): 512 elems, 2 per thread
        #pragma unroll
        for (int j = 0; j < 2; ++j) {
            int idx = tid + j * 256;
            int m2 = idx / BK, kk = idx % BK;
            int hq = h0 + m2, kg = k0 + kk;
            float v1 = 0.f, v2 = 0.f;
            if (hq < H && kg < H) {
                v1 = W[(size_t)hq * H + kg];
                v2 = W[(size_t)(hq + H) * H + kg];
            }
            Ws1[kk][m2] = v1;
            Ws2[kk][m2] = v2;
        }
        // Stage Y tile (16 k x 64 cols): 1024 elems, 4 per thread (coalesced)
        #pragma unroll
        for (int j = 0; j < 4; ++j) {
            int idx = tid + j * 256;
            int kk = idx >> 6, n = idx & 63;
            int kg = k0 + kk;
            Ys[kk][n] = (kg < H) ? y[(size_t)kg * L + l0 + n] : 0.f;
        }
        __syncthreads();

        #pragma unroll
        for (int kk = 0; kk < BK; ++kk) {
            float4 bv = *reinterpret_cast<const float4*>(&Ys[kk][tx * 4]);
            float a10 = Ws1[kk][ty * 2 + 0];
            float a11 = Ws1[kk][ty * 2 + 1];
            float a20 = Ws2[kk][ty * 2 + 0];
            float a21 = Ws2[kk][ty * 2 + 1];
            acc1[0][0] = fmaf(a10, bv.x, acc1[0][0]);
            acc1[0][1] = fmaf(a10, bv.y, acc1[0][1]);
            acc1[0][2] = fmaf(a10, bv.z, acc1[0][2]);
            acc1[0][3] = fmaf(a10, bv.w, acc1[0][3]);
            acc1[1][0] = fmaf(a11, bv.x, acc1[1][0]);
            acc1[1][1] = fmaf(a11, bv.y, acc1[1][1]);
            acc1[1][2] = fmaf(a11, bv.z, acc1[1][2]);
            acc1[1][3] = fmaf(a11, bv.w, acc1[1][3]);
            acc2[0][0] = fmaf(a20, bv.x, acc2[0][0]);
            acc2[0][1] = fmaf(a20, bv.y, acc2[0][1]);
            acc2[0][2] = fmaf(a20, bv.z, acc2[0][2]);
            acc2[0][3] = fmaf(a20, bv.w, acc2[0][3]);
            acc2[1][0] = fmaf(a21, bv.x, acc2[1][0]);
            acc2[1][1] = fmaf(a21, bv.y, acc2[1][1]);
            acc2[1][2] = fmaf(a21, bv.z, acc2[1][2]);
            acc2[1][3] = fmaf(a21, bv.w, acc2[1][3]);
        }
        __syncthreads();
    }

    #pragma unroll
    for (int r = 0; r < 2; ++r) {
        int hq = h0 + ty * 2 + r;
        if (hq >= H) continue;
        float b1v = bias[hq];
        float b2v = bias[hq + H];
        #pragma unroll
        for (int j = 0; j < 4; ++j) {
            int lq = l0 + tx * 4 + j;
            float v1 = acc1[r][j] + b1v;
            float v2 = acc2[r][j] + b2v;
            float g = v1 * (1.0f / (1.0f + expf(-v2)));
            out[(size_t)hq * L + lq] = g + zres[(size_t)hq * L + lq];
        }
    }
}

// ---------------------------------------------------------------------------
// LayerNorm over channel dim (per column l). Block: 64 cols x 4 h-stripes.
// ---------------------------------------------------------------------------
__global__ __launch_bounds__(256) void ln_kernel(
    const float* __restrict__ zpre,  // (H,L)
    const float* __restrict__ g,
    const float* __restrict__ b,
    float* __restrict__ out)         // (H,L)
{
    __shared__ float ssum[4][64];
    __shared__ float ssq[4][64];
    const int tx = threadIdx.x & 63;
    const int ty = threadIdx.x >> 6;
    const int l = blockIdx.x * 64 + tx;

    float s = 0.f, q = 0.f;
    for (int h = ty; h < H; h += 4) {
        float v = zpre[(size_t)h * L + l];
        s += v;
        q = fmaf(v, v, q);
    }
    ssum[ty][tx] = s;
    ssq[ty][tx] = q;
    __syncthreads();

    float S = ssum[0][tx] + ssum[1][tx] + ssum[2][tx] + ssum[3][tx];
    float Q = ssq[0][tx] + ssq[1][tx] + ssq[2][tx] + ssq[3][tx];
    const float invH = 1.0f / (float)H;
    float mu = S * invH;
    float var = Q * invH - mu * mu;
    float rstd = rsqrtf(var + LN_EPS);

    for (int h = ty; h < H; h += 4) {
        float v = zpre[(size_t)h * L + l];
        out[(size_t)h * L + l] = (v - mu) * rstd * g[h] + b[h];
    }
}

// ---------------------------------------------------------------------------
extern "C" void kernel_launch(void* const* d_in, const int* in_sizes, int n_in,
                              void* d_out, int out_size, void* d_ws, size_t ws_size,
                              hipStream_t stream) {
    const float* Z          = (const float*)d_in[0];
    const float* log_dt     = (const float*)d_in[1];
    const float* A_real_log = (const float*)d_in[2];
    const float* A_imag     = (const float*)d_in[3];
    const float* C_re       = (const float*)d_in[4];
    const float* C_im       = (const float*)d_in[5];
    const float* D_skip     = (const float*)d_in[6];
    const float* glu_w      = (const float*)d_in[7];
    const float* glu_b      = (const float*)d_in[8];
    const float* ln_g       = (const float*)d_in[9];
    const float* ln_b       = (const float*)d_in[10];

    float* out = (float*)d_out;
    float* ws  = (float*)d_ws;

    float* wr   = ws;
    float* wi   = wr + H * NST;
    float* cr   = wi + H * NST;
    float* ci   = cr + H * NST;
    float* zbuf = ci + H * NST;       // (H,L)
    float* ybuf = zbuf + (size_t)H * L;  // (H,L)

    precompute_coef<<<(H * NST + 255) / 256, 256, 0, stream>>>(
        log_dt, A_real_log, A_imag, C_re, C_im, wr, wi, cr, ci);

    for (int layer = 0; layer < NLAYERS; ++layer) {
        const float* zcur = (layer == 0) ? Z : zbuf;

        conv_kernel<<<(H + 1) / 2, 64, 0, stream>>>(
            zcur, wr, wi, cr, ci, D_skip, ybuf);

        dim3 gmm(L / BN, (H + BM - 1) / BM);
        glu_matmul<<<gmm, 256, 0, stream>>>(ybuf, glu_w, glu_b, zcur, out);

        float* lnout = (layer < NLAYERS - 1) ? zbuf : out;
        ln_kernel<<<L / 64, 256, 0, stream>>>(out, ln_g, ln_b, lnout);
    }
}

// Round 4
// 698.914 us; speedup vs baseline: 1.8752x; 1.8752x over previous
//
#include <hip/hip_runtime.h>
#include <math.h>

#define H 511
#define L 2048
#define NST 32
#define NLAYERS 4
#define LN_EPS 1e-5f
#define NCHUNK 16
#define TCH (L / NCHUNK)   // 128
#define HN (H * NST)       // 16352

// ---------------------------------------------------------------------------
// Precompute per-(h,n): w = exp(dt*A)  and  c = 2 * (C_re + i C_im) * (w-1)/A
// ---------------------------------------------------------------------------
__global__ __launch_bounds__(256) void precompute_coef(
    const float* __restrict__ log_dt,
    const float* __restrict__ A_real_log,
    const float* __restrict__ A_imag,
    const float* __restrict__ C_re,
    const float* __restrict__ C_im,
    float* __restrict__ wr_o, float* __restrict__ wi_o,
    float* __restrict__ cr_o, float* __restrict__ ci_o)
{
    int idx = blockIdx.x * blockDim.x + threadIdx.x;
    if (idx >= HN) return;
    int h = idx / NST;
    float Ar = -expf(A_real_log[idx]);
    float Ai = A_imag[idx];
    float dt = expf(log_dt[h]);
    float dr = Ar * dt, di = Ai * dt;
    float er = expf(dr);
    float wr = er * cosf(di);
    float wi = er * sinf(di);
    // q = (w - 1) / A   (complex divide)
    float den = Ar * Ar + Ai * Ai;
    float a = wr - 1.0f, b = wi;
    float inv = 1.0f / den;
    float qr = (a * Ar + b * Ai) * inv;
    float qi = (b * Ar - a * Ai) * inv;
    float crv = 2.0f * (C_re[idx] * qr - C_im[idx] * qi);
    float civ = 2.0f * (C_re[idx] * qi + C_im[idx] * qr);
    wr_o[idx] = wr; wi_o[idx] = wi; cr_o[idx] = crv; ci_o[idx] = civ;
}

// ---------------------------------------------------------------------------
// DPP helpers: sum across each 32-lane half; result lands in lanes 31 and 63.
// ---------------------------------------------------------------------------
template <int CTRL, int ROW_MASK>
__device__ __forceinline__ float dpp_add(float x) {
    int r = __builtin_amdgcn_update_dpp(0, __float_as_int(x), CTRL, ROW_MASK, 0xf, true);
    return x + __int_as_float(r);
}
__device__ __forceinline__ float reduce32_to_lane31(float p) {
    p = dpp_add<0x111, 0xf>(p);  // row_shr:1
    p = dpp_add<0x112, 0xf>(p);  // row_shr:2
    p = dpp_add<0x114, 0xf>(p);  // row_shr:4
    p = dpp_add<0x118, 0xf>(p);  // row_shr:8
    p = dpp_add<0x142, 0xa>(p);  // row_bcast:15 into rows 1,3
    return p;                    // lane31 = sum(0..31), lane63 = sum(32..63)
}

__device__ __forceinline__ float gelu_tanh(float v) {
    const float c0 = 0.7978845608028654f;  // sqrt(2/pi)
    float t = tanhf(c0 * (v + 0.044715f * v * v * v));
    return 0.5f * v * (1.0f + t);
}

// ---------------------------------------------------------------------------
// conv pass 1: per (channel-pair, chunk) wave, local scan from s=0 over T
// steps; write chunk-end state to bend (NCHUNK, H, NST) complex.
// ---------------------------------------------------------------------------
__global__ __launch_bounds__(64) void conv_pass1(
    const float* __restrict__ z,
    const float* __restrict__ wr_,
    const float* __restrict__ wi_,
    float* __restrict__ bend_r,
    float* __restrict__ bend_i)
{
    __shared__ float zs[2][TCH];
    const int half = threadIdx.x >> 5;
    const int lane = threadIdx.x & 31;
    const int h = blockIdx.x * 2 + half;
    const int hh = (h < H) ? h : (H - 1);
    const int c = blockIdx.y;

    const float* zrow = z + (size_t)hh * L + c * TCH;
    for (int i = lane; i < TCH; i += 32) zs[half][i] = zrow[i];

    const int cidx = hh * NST + lane;
    const float wr = wr_[cidx], wi = wi_[cidx];
    __syncthreads();

    float sr = 0.0f, si = 0.0f;
    #pragma unroll 4
    for (int l = 0; l < TCH; ++l) {
        float zl = zs[half][l];
        float nsr = fmaf(wr, sr, fmaf(-wi, si, zl));
        float nsi = fmaf(wr, si, wi * sr);
        sr = nsr; si = nsi;
    }
    if (h < H) {
        bend_r[(size_t)c * HN + cidx] = sr;
        bend_i[(size_t)c * HN + cidx] = si;
    }
}

// ---------------------------------------------------------------------------
// conv combine: one thread per (h,n). wT = w^TCH by squaring; serial scan over
// the 16 chunk-end states; overwrite bend[c] with the carry-in for chunk c.
// ---------------------------------------------------------------------------
__global__ __launch_bounds__(256) void conv_combine(
    const float* __restrict__ wr_,
    const float* __restrict__ wi_,
    float* __restrict__ bend_r,
    float* __restrict__ bend_i)
{
    int idx = blockIdx.x * blockDim.x + threadIdx.x;
    if (idx >= HN) return;
    float wtr = wr_[idx], wti = wi_[idx];
    // w^128: 7 complex squarings
    #pragma unroll
    for (int k = 0; k < 7; ++k) {
        float nr = wtr * wtr - wti * wti;
        float ni = 2.0f * wtr * wti;
        wtr = nr; wti = ni;
    }
    float er = 0.0f, ei = 0.0f;   // E[c-1], carry entering chunk c
    #pragma unroll
    for (int c = 0; c < NCHUNK; ++c) {
        size_t p = (size_t)c * HN + idx;
        float sr = bend_r[p];
        float si = bend_i[p];
        bend_r[p] = er;           // carry-in for chunk c
        bend_i[p] = ei;
        // E[c] = S_local_end[c] + wT * E[c-1]
        float ner = fmaf(wtr, er, fmaf(-wti, ei, sr));
        float nei = fmaf(wtr, ei, fmaf(wti, er, si));
        er = ner; ei = nei;
    }
}

// ---------------------------------------------------------------------------
// conv pass 2: recurrence with carry-in + C-dot + DPP reduce + D-skip + gelu.
// ---------------------------------------------------------------------------
__global__ __launch_bounds__(64) void conv_pass2(
    const float* __restrict__ z,
    const float* __restrict__ wr_,
    const float* __restrict__ wi_,
    const float* __restrict__ cr_,
    const float* __restrict__ ci_,
    const float* __restrict__ bend_r,
    const float* __restrict__ bend_i,
    const float* __restrict__ D_skip,
    float* __restrict__ y)
{
    __shared__ float zs[2][TCH];
    __shared__ float ys[2][TCH];
    const int half = threadIdx.x >> 5;
    const int lane = threadIdx.x & 31;
    const int h = blockIdx.x * 2 + half;
    const int hh = (h < H) ? h : (H - 1);
    const int c = blockIdx.y;

    const float* zrow = z + (size_t)hh * L + c * TCH;
    for (int i = lane; i < TCH; i += 32) zs[half][i] = zrow[i];

    const int cidx = hh * NST + lane;
    const float wr = wr_[cidx], wi = wi_[cidx];
    const float cr = cr_[cidx], ci = ci_[cidx];
    const float Dh = D_skip[hh];
    float sr = bend_r[(size_t)c * HN + cidx];
    float si = bend_i[(size_t)c * HN + cidx];
    __syncthreads();

    for (int l = 0; l < TCH; ++l) {
        float zl = zs[half][l];
        float nsr = fmaf(wr, sr, fmaf(-wi, si, zl));
        float nsi = fmaf(wr, si, wi * sr);
        sr = nsr; si = nsi;
        float p = fmaf(cr, sr, -ci * si);
        p = reduce32_to_lane31(p);
        if (lane == 31) ys[half][l] = fmaf(Dh, zl, p);
    }
    __syncthreads();

    if (h < H) {
        float* yrow = y + (size_t)h * L + c * TCH;
        for (int i = lane; i < TCH; i += 32) yrow[i] = gelu_tanh(ys[half][i]);
    }
}

// ---------------------------------------------------------------------------
// Fused: y2 = glu_w @ y + glu_b ; out = y2[:H]*sigmoid(y2[H:]) + residual
// ---------------------------------------------------------------------------
#define BM 32
#define BN 64
#define BK 16
__global__ __launch_bounds__(256) void glu_matmul(
    const float* __restrict__ y,     // (H,L)
    const float* __restrict__ W,     // (2H,H)
    const float* __restrict__ bias,  // (2H)
    const float* __restrict__ zres,  // (H,L) residual
    float* __restrict__ out)         // (H,L)
{
    __shared__ __align__(16) float Ws1[BK][BM];
    __shared__ __align__(16) float Ws2[BK][BM];
    __shared__ __align__(16) float Ys[BK][BN];

    const int tid = threadIdx.x;
    const int h0 = blockIdx.y * BM;
    const int l0 = blockIdx.x * BN;
    const int tx = tid & 15;
    const int ty = tid >> 4;

    float acc1[2][4] = {{0.f,0.f,0.f,0.f},{0.f,0.f,0.f,0.f}};
    float acc2[2][4] = {{0.f,0.f,0.f,0.f},{0.f,0.f,0.f,0.f}};

    for (int k0 = 0; k0 < H; k0 += BK) {
        #pragma unroll
        for (int j = 0; j < 2; ++j) {
            int idx = tid + j * 256;
            int m2 = idx / BK, kk = idx % BK;
            int hq = h0 + m2, kg = k0 + kk;
            float v1 = 0.f, v2 = 0.f;
            if (hq < H && kg < H) {
                v1 = W[(size_t)hq * H + kg];
                v2 = W[(size_t)(hq + H) * H + kg];
            }
            Ws1[kk][m2] = v1;
            Ws2[kk][m2] = v2;
        }
        #pragma unroll
        for (int j = 0; j < 4; ++j) {
            int idx = tid + j * 256;
            int kk = idx >> 6, n = idx & 63;
            int kg = k0 + kk;
            Ys[kk][n] = (kg < H) ? y[(size_t)kg * L + l0 + n] : 0.f;
        }
        __syncthreads();

        #pragma unroll
        for (int kk = 0; kk < BK; ++kk) {
            float4 bv = *reinterpret_cast<const float4*>(&Ys[kk][tx * 4]);
            float a10 = Ws1[kk][ty * 2 + 0];
            float a11 = Ws1[kk][ty * 2 + 1];
            float a20 = Ws2[kk][ty * 2 + 0];
            float a21 = Ws2[kk][ty * 2 + 1];
            acc1[0][0] = fmaf(a10, bv.x, acc1[0][0]);
            acc1[0][1] = fmaf(a10, bv.y, acc1[0][1]);
            acc1[0][2] = fmaf(a10, bv.z, acc1[0][2]);
            acc1[0][3] = fmaf(a10, bv.w, acc1[0][3]);
            acc1[1][0] = fmaf(a11, bv.x, acc1[1][0]);
            acc1[1][1] = fmaf(a11, bv.y, acc1[1][1]);
            acc1[1][2] = fmaf(a11, bv.z, acc1[1][2]);
            acc1[1][3] = fmaf(a11, bv.w, acc1[1][3]);
            acc2[0][0] = fmaf(a20, bv.x, acc2[0][0]);
            acc2[0][1] = fmaf(a20, bv.y, acc2[0][1]);
            acc2[0][2] = fmaf(a20, bv.z, acc2[0][2]);
            acc2[0][3] = fmaf(a20, bv.w, acc2[0][3]);
            acc2[1][0] = fmaf(a21, bv.x, acc2[1][0]);
            acc2[1][1] = fmaf(a21, bv.y, acc2[1][1]);
            acc2[1][2] = fmaf(a21, bv.z, acc2[1][2]);
            acc2[1][3] = fmaf(a21, bv.w, acc2[1][3]);
        }
        __syncthreads();
    }

    #pragma unroll
    for (int r = 0; r < 2; ++r) {
        int hq = h0 + ty * 2 + r;
        if (hq >= H) continue;
        float b1v = bias[hq];
        float b2v = bias[hq + H];
        #pragma unroll
        for (int j = 0; j < 4; ++j) {
            int lq = l0 + tx * 4 + j;
            float v1 = acc1[r][j] + b1v;
            float v2 = acc2[r][j] + b2v;
            float g = v1 * (1.0f / (1.0f + expf(-v2)));
            out[(size_t)hq * L + lq] = g + zres[(size_t)hq * L + lq];
        }
    }
}

// ---------------------------------------------------------------------------
// LayerNorm over channel dim (per column l). Block: 64 cols x 4 h-stripes.
// ---------------------------------------------------------------------------
__global__ __launch_bounds__(256) void ln_kernel(
    const float* __restrict__ zpre,
    const float* __restrict__ g,
    const float* __restrict__ b,
    float* __restrict__ out)
{
    __shared__ float ssum[4][64];
    __shared__ float ssq[4][64];
    const int tx = threadIdx.x & 63;
    const int ty = threadIdx.x >> 6;
    const int l = blockIdx.x * 64 + tx;

    float s = 0.f, q = 0.f;
    for (int h = ty; h < H; h += 4) {
        float v = zpre[(size_t)h * L + l];
        s += v;
        q = fmaf(v, v, q);
    }
    ssum[ty][tx] = s;
    ssq[ty][tx] = q;
    __syncthreads();

    float S = ssum[0][tx] + ssum[1][tx] + ssum[2][tx] + ssum[3][tx];
    float Q = ssq[0][tx] + ssq[1][tx] + ssq[2][tx] + ssq[3][tx];
    const float invH = 1.0f / (float)H;
    float mu = S * invH;
    float var = Q * invH - mu * mu;
    float rstd = rsqrtf(var + LN_EPS);

    for (int h = ty; h < H; h += 4) {
        float v = zpre[(size_t)h * L + l];
        out[(size_t)h * L + l] = (v - mu) * rstd * g[h] + b[h];
    }
}

// ---------------------------------------------------------------------------
extern "C" void kernel_launch(void* const* d_in, const int* in_sizes, int n_in,
                              void* d_out, int out_size, void* d_ws, size_t ws_size,
                              hipStream_t stream) {
    const float* Z          = (const float*)d_in[0];
    const float* log_dt     = (const float*)d_in[1];
    const float* A_real_log = (const float*)d_in[2];
    const float* A_imag     = (const float*)d_in[3];
    const float* C_re       = (const float*)d_in[4];
    const float* C_im       = (const float*)d_in[5];
    const float* D_skip     = (const float*)d_in[6];
    const float* glu_w      = (const float*)d_in[7];
    const float* glu_b      = (const float*)d_in[8];
    const float* ln_g       = (const float*)d_in[9];
    const float* ln_b       = (const float*)d_in[10];

    float* out = (float*)d_out;
    float* ws  = (float*)d_ws;

    float* wr     = ws;
    float* wi     = wr + HN;
    float* cr     = wi + HN;
    float* ci     = cr + HN;
    float* zbuf   = ci + HN;                    // (H,L)
    float* ybuf   = zbuf + (size_t)H * L;       // (H,L)
    float* bend_r = ybuf + (size_t)H * L;       // (NCHUNK,H,NST)
    float* bend_i = bend_r + (size_t)NCHUNK * HN;

    precompute_coef<<<(HN + 255) / 256, 256, 0, stream>>>(
        log_dt, A_real_log, A_imag, C_re, C_im, wr, wi, cr, ci);

    const dim3 cg((H + 1) / 2, NCHUNK);
    for (int layer = 0; layer < NLAYERS; ++layer) {
        const float* zcur = (layer == 0) ? Z : zbuf;

        conv_pass1<<<cg, 64, 0, stream>>>(zcur, wr, wi, bend_r, bend_i);
        conv_combine<<<(HN + 255) / 256, 256, 0, stream>>>(wr, wi, bend_r, bend_i);
        conv_pass2<<<cg, 64, 0, stream>>>(zcur, wr, wi, cr, ci,
                                          bend_r, bend_i, D_skip, ybuf);

        dim3 gmm(L / BN, (H + BM - 1) / BM);
        glu_matmul<<<gmm, 256, 0, stream>>>(ybuf, glu_w, glu_b, zcur, out);

        float* lnout = (layer < NLAYERS - 1) ? zbuf : out;
        ln_kernel<<<L / 64, 256, 0, stream>>>(out, ln_g, ln_b, lnout);
    }
}

// Round 5
// 407.134 us; speedup vs baseline: 3.2191x; 1.7167x over previous
//
#include <hip/hip_runtime.h>
#include <hip/hip_bf16.h>
#include <math.h>

#define H 511
#define L 2048
#define NST 32
#define NLAYERS 4
#define LN_EPS 1e-5f
#define NCHUNK 16
#define TCH (L / NCHUNK)   // 128
#define HN (H * NST)       // 16352
#define HP 512             // K padded
#define GBK 64
#define GBN 64

typedef __attribute__((ext_vector_type(8))) short short8;
typedef __attribute__((ext_vector_type(4))) float f32x4;

__device__ __forceinline__ ushort f2bf(float v) {
    __hip_bfloat16 b = __float2bfloat16(v);
    return *reinterpret_cast<ushort*>(&b);
}

// ---------------------------------------------------------------------------
// Precompute per-(h,n): w = exp(dt*A)  and  c = 2 * (C_re + i C_im) * (w-1)/A
// ---------------------------------------------------------------------------
__global__ __launch_bounds__(256) void precompute_coef(
    const float* __restrict__ log_dt,
    const float* __restrict__ A_real_log,
    const float* __restrict__ A_imag,
    const float* __restrict__ C_re,
    const float* __restrict__ C_im,
    float* __restrict__ wr_o, float* __restrict__ wi_o,
    float* __restrict__ cr_o, float* __restrict__ ci_o)
{
    int idx = blockIdx.x * blockDim.x + threadIdx.x;
    if (idx >= HN) return;
    int h = idx / NST;
    float Ar = -expf(A_real_log[idx]);
    float Ai = A_imag[idx];
    float dt = expf(log_dt[h]);
    float dr = Ar * dt, di = Ai * dt;
    float er = expf(dr);
    float wr = er * cosf(di);
    float wi = er * sinf(di);
    float den = Ar * Ar + Ai * Ai;
    float a = wr - 1.0f, b = wi;
    float inv = 1.0f / den;
    float qr = (a * Ar + b * Ai) * inv;
    float qi = (b * Ar - a * Ai) * inv;
    float crv = 2.0f * (C_re[idx] * qr - C_im[idx] * qi);
    float civ = 2.0f * (C_re[idx] * qi + C_im[idx] * qr);
    wr_o[idx] = wr; wi_o[idx] = wi; cr_o[idx] = crv; ci_o[idx] = civ;
}

// ---------------------------------------------------------------------------
// W (2H,H) fp32 -> (2H,HP) bf16, zero-padded K
// ---------------------------------------------------------------------------
__global__ __launch_bounds__(256) void w_to_bf16(
    const float* __restrict__ W, ushort* __restrict__ wbf)
{
    int idx = blockIdx.x * 256 + threadIdx.x;
    if (idx >= 2 * H * HP) return;
    int r = idx / HP, k = idx % HP;
    float v = (k < H) ? W[(size_t)r * H + k] : 0.0f;
    wbf[idx] = f2bf(v);
}

// ---------------------------------------------------------------------------
// DPP helpers: sum across each 32-lane half; result lands in lanes 31 and 63.
// ---------------------------------------------------------------------------
template <int CTRL, int ROW_MASK>
__device__ __forceinline__ float dpp_add(float x) {
    int r = __builtin_amdgcn_update_dpp(0, __float_as_int(x), CTRL, ROW_MASK, 0xf, true);
    return x + __int_as_float(r);
}
__device__ __forceinline__ float reduce32_to_lane31(float p) {
    p = dpp_add<0x111, 0xf>(p);  // row_shr:1
    p = dpp_add<0x112, 0xf>(p);  // row_shr:2
    p = dpp_add<0x114, 0xf>(p);  // row_shr:4
    p = dpp_add<0x118, 0xf>(p);  // row_shr:8
    p = dpp_add<0x142, 0xa>(p);  // row_bcast:15 into rows 1,3
    return p;
}

__device__ __forceinline__ float gelu_tanh(float v) {
    const float c0 = 0.7978845608028654f;  // sqrt(2/pi)
    float t = tanhf(c0 * (v + 0.044715f * v * v * v));
    return 0.5f * v * (1.0f + t);
}

// ---------------------------------------------------------------------------
// conv pass 1: local scan per (channel-pair, chunk); write chunk-end state.
// ---------------------------------------------------------------------------
__global__ __launch_bounds__(64) void conv_pass1(
    const float* __restrict__ z,
    const float* __restrict__ wr_,
    const float* __restrict__ wi_,
    float* __restrict__ bend_r,
    float* __restrict__ bend_i)
{
    __shared__ float zs[2][TCH];
    const int half = threadIdx.x >> 5;
    const int lane = threadIdx.x & 31;
    const int h = blockIdx.x * 2 + half;
    const int hh = (h < H) ? h : (H - 1);
    const int c = blockIdx.y;

    const float* zrow = z + (size_t)hh * L + c * TCH;
    for (int i = lane; i < TCH; i += 32) zs[half][i] = zrow[i];

    const int cidx = hh * NST + lane;
    const float wr = wr_[cidx], wi = wi_[cidx];
    __syncthreads();

    float sr = 0.0f, si = 0.0f;
    #pragma unroll 4
    for (int l = 0; l < TCH; ++l) {
        float zl = zs[half][l];
        float nsr = fmaf(wr, sr, fmaf(-wi, si, zl));
        float nsi = fmaf(wr, si, wi * sr);
        sr = nsr; si = nsi;
    }
    if (h < H) {
        bend_r[(size_t)c * HN + cidx] = sr;
        bend_i[(size_t)c * HN + cidx] = si;
    }
}

// ---------------------------------------------------------------------------
// conv combine: per (h,n): wT = w^TCH; serial 16-step scan -> carry-ins.
// ---------------------------------------------------------------------------
__global__ __launch_bounds__(256) void conv_combine(
    const float* __restrict__ wr_,
    const float* __restrict__ wi_,
    float* __restrict__ bend_r,
    float* __restrict__ bend_i)
{
    int idx = blockIdx.x * blockDim.x + threadIdx.x;
    if (idx >= HN) return;
    float wtr = wr_[idx], wti = wi_[idx];
    #pragma unroll
    for (int k = 0; k < 7; ++k) {
        float nr = wtr * wtr - wti * wti;
        float ni = 2.0f * wtr * wti;
        wtr = nr; wti = ni;
    }
    float er = 0.0f, ei = 0.0f;
    #pragma unroll
    for (int c = 0; c < NCHUNK; ++c) {
        size_t p = (size_t)c * HN + idx;
        float sr = bend_r[p];
        float si = bend_i[p];
        bend_r[p] = er;
        bend_i[p] = ei;
        float ner = fmaf(wtr, er, fmaf(-wti, ei, sr));
        float nei = fmaf(wtr, ei, fmaf(wti, er, si));
        er = ner; ei = nei;
    }
}

// ---------------------------------------------------------------------------
// conv pass 2: recurrence with carry-in + C-dot + DPP reduce + D-skip + gelu.
// Writes y as bf16 (H,L).
// ---------------------------------------------------------------------------
__global__ __launch_bounds__(64) void conv_pass2(
    const float* __restrict__ z,
    const float* __restrict__ wr_,
    const float* __restrict__ wi_,
    const float* __restrict__ cr_,
    const float* __restrict__ ci_,
    const float* __restrict__ bend_r,
    const float* __restrict__ bend_i,
    const float* __restrict__ D_skip,
    ushort* __restrict__ yb)
{
    __shared__ float zs[2][TCH];
    __shared__ float ys[2][TCH];
    const int half = threadIdx.x >> 5;
    const int lane = threadIdx.x & 31;
    const int h = blockIdx.x * 2 + half;
    const int hh = (h < H) ? h : (H - 1);
    const int c = blockIdx.y;

    const float* zrow = z + (size_t)hh * L + c * TCH;
    for (int i = lane; i < TCH; i += 32) zs[half][i] = zrow[i];

    const int cidx = hh * NST + lane;
    const float wr = wr_[cidx], wi = wi_[cidx];
    const float cr = cr_[cidx], ci = ci_[cidx];
    const float Dh = D_skip[hh];
    float sr = bend_r[(size_t)c * HN + cidx];
    float si = bend_i[(size_t)c * HN + cidx];
    __syncthreads();

    for (int l = 0; l < TCH; ++l) {
        float zl = zs[half][l];
        float nsr = fmaf(wr, sr, fmaf(-wi, si, zl));
        float nsi = fmaf(wr, si, wi * sr);
        sr = nsr; si = nsi;
        float p = fmaf(cr, sr, -ci * si);
        p = reduce32_to_lane31(p);
        if (lane == 31) ys[half][l] = fmaf(Dh, zl, p);
    }
    __syncthreads();

    if (h < H) {
        ushort* yrow = yb + (size_t)h * L + c * TCH;
        for (int i = lane; i < TCH; i += 32) yrow[i] = f2bf(gelu_tanh(ys[half][i]));
    }
}

// ---------------------------------------------------------------------------
// Transpose y bf16 (H,L) -> ytb bf16 (L,HP), zero-filling h=511.
// ---------------------------------------------------------------------------
__global__ __launch_bounds__(256) void ytr_kernel(
    const ushort* __restrict__ yb,
    ushort* __restrict__ ytb)
{
    __shared__ ushort t[32][34];
    const int tx = threadIdx.x;      // 0..31
    const int ty = threadIdx.y;      // 0..7
    const int l0 = blockIdx.x * 32;
    const int h0 = blockIdx.y * 32;
    #pragma unroll
    for (int j = 0; j < 4; ++j) {
        int h = h0 + ty + j * 8;
        ushort v = 0;
        if (h < H) v = yb[(size_t)h * L + l0 + tx];
        t[tx][ty + j * 8] = v;       // t[l_local][h_local]
    }
    __syncthreads();
    #pragma unroll
    for (int j = 0; j < 4; ++j) {
        int l = l0 + ty + j * 8;
        ytb[(size_t)l * HP + h0 + tx] = t[ty + j * 8][tx];
    }
}

// ---------------------------------------------------------------------------
// MFMA GLU GEMM: C = wbf (2H,HP) . ytb^T (HP,L); GLU over gate pairs +
// residual. Block: 32 gate-paired rows x 64 cols, 4 waves (2x2), BK=64,
// XOR-swizzled LDS (kgrp ^= row&7) on write AND read -> conflict-free.
// ---------------------------------------------------------------------------
__global__ __launch_bounds__(256) void glu_mfma(
    const ushort* __restrict__ wbf,   // (2H, HP) bf16
    const ushort* __restrict__ ytb,   // (L, HP) bf16
    const float* __restrict__ bias,   // (2H)
    const float* __restrict__ zres,   // (H,L)
    float* __restrict__ out)          // (H,L)
{
    __shared__ ushort As1[32 * GBK];
    __shared__ ushort As2[32 * GBK];
    __shared__ ushort Bs[GBN * GBK];

    const int tid = threadIdx.x;
    const int h0 = blockIdx.y * 32;
    const int l0 = blockIdx.x * GBN;
    const int wid = tid >> 6;
    const int lane = tid & 63;
    const int wrow = (wid >> 1) * 16;    // 0 or 16
    const int wcol = (wid & 1) * 32;     // 0 or 32

    f32x4 acc1[2] = {{0.f,0.f,0.f,0.f},{0.f,0.f,0.f,0.f}};
    f32x4 acc2[2] = {{0.f,0.f,0.f,0.f},{0.f,0.f,0.f,0.f}};

    // staging indices: thread -> (row 0..31, kgrp 0..7)
    const int ar = tid >> 3;
    const int ak = tid & 7;
    const int hq1 = (h0 + ar < H) ? (h0 + ar) : (H - 1);   // clamp; tail rows discarded at store
    const int hq2 = hq1 + H;
    const int aswz = ak ^ (ar & 7);

    for (int k0 = 0; k0 < HP; k0 += GBK) {
        short8 va1 = *(const short8*)&wbf[(size_t)hq1 * HP + k0 + ak * 8];
        short8 va2 = *(const short8*)&wbf[(size_t)hq2 * HP + k0 + ak * 8];
        *(short8*)&As1[ar * GBK + aswz * 8] = va1;
        *(short8*)&As2[ar * GBK + aswz * 8] = va2;
        #pragma unroll
        for (int j = 0; j < 2; ++j) {
            int idx = tid + j * 256;
            int br = idx >> 3;       // l-local 0..63
            int bk = idx & 7;
            short8 vb = *(const short8*)&ytb[(size_t)(l0 + br) * HP + k0 + bk * 8];
            *(short8*)&Bs[br * GBK + (bk ^ (br & 7)) * 8] = vb;
        }
        __syncthreads();

        #pragma unroll
        for (int kk = 0; kk < 2; ++kk) {
            const int arow = wrow + (lane & 15);
            const int kg = kk * 4 + (lane >> 4);
            short8 a1 = *(const short8*)&As1[arow * GBK + (kg ^ (arow & 7)) * 8];
            short8 a2 = *(const short8*)&As2[arow * GBK + (kg ^ (arow & 7)) * 8];
            #pragma unroll
            for (int nf = 0; nf < 2; ++nf) {
                const int brow = wcol + nf * 16 + (lane & 15);
                short8 b = *(const short8*)&Bs[brow * GBK + (kg ^ (brow & 7)) * 8];
                acc1[nf] = __builtin_amdgcn_mfma_f32_16x16x32_bf16(a1, b, acc1[nf], 0, 0, 0);
                acc2[nf] = __builtin_amdgcn_mfma_f32_16x16x32_bf16(a2, b, acc2[nf], 0, 0, 0);
            }
        }
        __syncthreads();
    }

    // epilogue: C/D layout col=lane&15, row=(lane>>4)*4+reg  [m89-verified]
    #pragma unroll
    for (int nf = 0; nf < 2; ++nf) {
        const int col = l0 + wcol + nf * 16 + (lane & 15);
        #pragma unroll
        for (int r = 0; r < 4; ++r) {
            const int h = h0 + wrow + (lane >> 4) * 4 + r;
            if (h < H) {
                float v1 = acc1[nf][r] + bias[h];
                float v2 = acc2[nf][r] + bias[h + H];
                float g = v1 * (1.0f / (1.0f + expf(-v2)));
                out[(size_t)h * L + col] = g + zres[(size_t)h * L + col];
            }
        }
    }
}

// ---------------------------------------------------------------------------
// LayerNorm over channel dim (per column l). Block: 64 cols x 4 h-stripes.
// ---------------------------------------------------------------------------
__global__ __launch_bounds__(256) void ln_kernel(
    const float* __restrict__ zpre,
    const float* __restrict__ g,
    const float* __restrict__ b,
    float* __restrict__ out)
{
    __shared__ float ssum[4][64];
    __shared__ float ssq[4][64];
    const int tx = threadIdx.x & 63;
    const int ty = threadIdx.x >> 6;
    const int l = blockIdx.x * 64 + tx;

    float s = 0.f, q = 0.f;
    for (int h = ty; h < H; h += 4) {
        float v = zpre[(size_t)h * L + l];
        s += v;
        q = fmaf(v, v, q);
    }
    ssum[ty][tx] = s;
    ssq[ty][tx] = q;
    __syncthreads();

    float S = ssum[0][tx] + ssum[1][tx] + ssum[2][tx] + ssum[3][tx];
    float Q = ssq[0][tx] + ssq[1][tx] + ssq[2][tx] + ssq[3][tx];
    const float invH = 1.0f / (float)H;
    float mu = S * invH;
    float var = Q * invH - mu * mu;
    float rstd = rsqrtf(var + LN_EPS);

    for (int h = ty; h < H; h += 4) {
        float v = zpre[(size_t)h * L + l];
        out[(size_t)h * L + l] = (v - mu) * rstd * g[h] + b[h];
    }
}

// ---------------------------------------------------------------------------
extern "C" void kernel_launch(void* const* d_in, const int* in_sizes, int n_in,
                              void* d_out, int out_size, void* d_ws, size_t ws_size,
                              hipStream_t stream) {
    const float* Z          = (const float*)d_in[0];
    const float* log_dt     = (const float*)d_in[1];
    const float* A_real_log = (const float*)d_in[2];
    const float* A_imag     = (const float*)d_in[3];
    const float* C_re       = (const float*)d_in[4];
    const float* C_im       = (const float*)d_in[5];
    const float* D_skip     = (const float*)d_in[6];
    const float* glu_w      = (const float*)d_in[7];
    const float* glu_b      = (const float*)d_in[8];
    const float* ln_g       = (const float*)d_in[9];
    const float* ln_b       = (const float*)d_in[10];

    float* out = (float*)d_out;
    float* ws  = (float*)d_ws;

    // fp32 regions (all multiples of 16 floats -> 16B-aligned)
    float* wr     = ws;
    float* wi     = wr + HN;
    float* cr     = wi + HN;
    float* ci     = cr + HN;
    float* zbuf   = ci + HN;                          // (H,L) fp32
    float* bend_r = zbuf + (size_t)H * L;             // (NCHUNK,HN)
    float* bend_i = bend_r + (size_t)NCHUNK * HN;
    // bf16 regions
    ushort* yb  = (ushort*)(bend_i + (size_t)NCHUNK * HN);  // (H,L) bf16
    ushort* ytb = yb + (size_t)H * L;                        // (L,HP) bf16
    ushort* wbf = ytb + (size_t)L * HP;                      // (2H,HP) bf16

    precompute_coef<<<(HN + 255) / 256, 256, 0, stream>>>(
        log_dt, A_real_log, A_imag, C_re, C_im, wr, wi, cr, ci);
    w_to_bf16<<<(2 * H * HP + 255) / 256, 256, 0, stream>>>(glu_w, wbf);

    const dim3 cg((H + 1) / 2, NCHUNK);
    const dim3 tg(L / 32, HP / 32);
    const dim3 tb(32, 8);
    const dim3 gg(L / GBN, (H + 31) / 32);

    for (int layer = 0; layer < NLAYERS; ++layer) {
        const float* zcur = (layer == 0) ? Z : zbuf;

        conv_pass1<<<cg, 64, 0, stream>>>(zcur, wr, wi, bend_r, bend_i);
        conv_combine<<<(HN + 255) / 256, 256, 0, stream>>>(wr, wi, bend_r, bend_i);
        conv_pass2<<<cg, 64, 0, stream>>>(zcur, wr, wi, cr, ci,
                                          bend_r, bend_i, D_skip, yb);
        ytr_kernel<<<tg, tb, 0, stream>>>(yb, ytb);
        glu_mfma<<<gg, 256, 0, stream>>>(wbf, ytb, glu_b, zcur, out);

        float* lnout = (layer < NLAYERS - 1) ? zbuf : out;
        ln_kernel<<<L / 64, 256, 0, stream>>>(out, ln_g, ln_b, lnout);
    }
}

// Round 6
// 285.552 us; speedup vs baseline: 4.5897x; 1.4258x over previous
//
#include <hip/hip_runtime.h>
#include <hip/hip_bf16.h>
#include <math.h>

#define H 511
#define L 2048
#define NST 32
#define NLAYERS 4
#define LN_EPS 1e-5f
#define NCHUNK 16
#define TCH (L / NCHUNK)   // 128
#define HN (H * NST)       // 16352
#define HP 512             // K padded
#define GBK 64
#define GBN 64
#define NSTRIPE 16         // LN h-stripes of 32

typedef __attribute__((ext_vector_type(8))) short short8;
typedef __attribute__((ext_vector_type(4))) float f32x4;

__device__ __forceinline__ ushort f2bf(float v) {
    __hip_bfloat16 b = __float2bfloat16(v);
    return *reinterpret_cast<ushort*>(&b);
}

// ---------------------------------------------------------------------------
// Precompute per-(h,n): w = exp(dt*A)  and  c = 2 * (C_re + i C_im) * (w-1)/A
// ---------------------------------------------------------------------------
__global__ __launch_bounds__(256) void precompute_coef(
    const float* __restrict__ log_dt,
    const float* __restrict__ A_real_log,
    const float* __restrict__ A_imag,
    const float* __restrict__ C_re,
    const float* __restrict__ C_im,
    float* __restrict__ wr_o, float* __restrict__ wi_o,
    float* __restrict__ cr_o, float* __restrict__ ci_o)
{
    int idx = blockIdx.x * blockDim.x + threadIdx.x;
    if (idx >= HN) return;
    int h = idx / NST;
    float Ar = -expf(A_real_log[idx]);
    float Ai = A_imag[idx];
    float dt = expf(log_dt[h]);
    float dr = Ar * dt, di = Ai * dt;
    float er = expf(dr);
    float wr = er * cosf(di);
    float wi = er * sinf(di);
    float den = Ar * Ar + Ai * Ai;
    float a = wr - 1.0f, b = wi;
    float inv = 1.0f / den;
    float qr = (a * Ar + b * Ai) * inv;
    float qi = (b * Ar - a * Ai) * inv;
    float crv = 2.0f * (C_re[idx] * qr - C_im[idx] * qi);
    float civ = 2.0f * (C_re[idx] * qi + C_im[idx] * qr);
    wr_o[idx] = wr; wi_o[idx] = wi; cr_o[idx] = crv; ci_o[idx] = civ;
}

// ---------------------------------------------------------------------------
// W (2H,H) fp32 -> (2H,HP) bf16, zero-padded K
// ---------------------------------------------------------------------------
__global__ __launch_bounds__(256) void w_to_bf16(
    const float* __restrict__ W, ushort* __restrict__ wbf)
{
    int idx = blockIdx.x * 256 + threadIdx.x;
    if (idx >= 2 * H * HP) return;
    int r = idx / HP, k = idx % HP;
    float v = (k < H) ? W[(size_t)r * H + k] : 0.0f;
    wbf[idx] = f2bf(v);
}

// ---------------------------------------------------------------------------
// DPP helpers: sum across each 32-lane half; result lands in lanes 31 and 63.
// ---------------------------------------------------------------------------
template <int CTRL, int ROW_MASK>
__device__ __forceinline__ float dpp_add(float x) {
    int r = __builtin_amdgcn_update_dpp(0, __float_as_int(x), CTRL, ROW_MASK, 0xf, true);
    return x + __int_as_float(r);
}
__device__ __forceinline__ float reduce32_to_lane31(float p) {
    p = dpp_add<0x111, 0xf>(p);  // row_shr:1
    p = dpp_add<0x112, 0xf>(p);  // row_shr:2
    p = dpp_add<0x114, 0xf>(p);  // row_shr:4
    p = dpp_add<0x118, 0xf>(p);  // row_shr:8
    p = dpp_add<0x142, 0xa>(p);  // row_bcast:15 into rows 1,3
    return p;
}

__device__ __forceinline__ float gelu_tanh(float v) {
    const float c0 = 0.7978845608028654f;  // sqrt(2/pi)
    float t = tanhf(c0 * (v + 0.044715f * v * v * v));
    return 0.5f * v * (1.0f + t);
}

// ---------------------------------------------------------------------------
// conv pass 1: local scan per (channel-pair, chunk); write chunk-end state.
// ---------------------------------------------------------------------------
__global__ __launch_bounds__(64) void conv_pass1(
    const float* __restrict__ z,
    const float* __restrict__ wr_,
    const float* __restrict__ wi_,
    float* __restrict__ bend_r,
    float* __restrict__ bend_i)
{
    __shared__ float zs[2][TCH];
    const int half = threadIdx.x >> 5;
    const int lane = threadIdx.x & 31;
    const int h = blockIdx.x * 2 + half;
    const int hh = (h < H) ? h : (H - 1);
    const int c = blockIdx.y;

    const float* zrow = z + (size_t)hh * L + c * TCH;
    for (int i = lane; i < TCH; i += 32) zs[half][i] = zrow[i];

    const int cidx = hh * NST + lane;
    const float wr = wr_[cidx], wi = wi_[cidx];
    __syncthreads();

    float sr = 0.0f, si = 0.0f;
    #pragma unroll 4
    for (int l = 0; l < TCH; ++l) {
        float zl = zs[half][l];
        float nsr = fmaf(wr, sr, fmaf(-wi, si, zl));
        float nsi = fmaf(wr, si, wi * sr);
        sr = nsr; si = nsi;
    }
    if (h < H) {
        bend_r[(size_t)c * HN + cidx] = sr;
        bend_i[(size_t)c * HN + cidx] = si;
    }
}

// ---------------------------------------------------------------------------
// conv combine: per (h,n): wT = w^TCH; serial 16-step scan -> carry-ins.
// ---------------------------------------------------------------------------
__global__ __launch_bounds__(256) void conv_combine(
    const float* __restrict__ wr_,
    const float* __restrict__ wi_,
    float* __restrict__ bend_r,
    float* __restrict__ bend_i)
{
    int idx = blockIdx.x * blockDim.x + threadIdx.x;
    if (idx >= HN) return;
    float wtr = wr_[idx], wti = wi_[idx];
    #pragma unroll
    for (int k = 0; k < 7; ++k) {
        float nr = wtr * wtr - wti * wti;
        float ni = 2.0f * wtr * wti;
        wtr = nr; wti = ni;
    }
    float er = 0.0f, ei = 0.0f;
    #pragma unroll
    for (int c = 0; c < NCHUNK; ++c) {
        size_t p = (size_t)c * HN + idx;
        float sr = bend_r[p];
        float si = bend_i[p];
        bend_r[p] = er;
        bend_i[p] = ei;
        float ner = fmaf(wtr, er, fmaf(-wti, ei, sr));
        float nei = fmaf(wtr, ei, fmaf(wti, er, si));
        er = ner; ei = nei;
    }
}

// ---------------------------------------------------------------------------
// conv pass 2: recurrence with carry-in + C-dot + DPP reduce + D-skip + gelu.
// Writes y as bf16 (H,L).
// ---------------------------------------------------------------------------
__global__ __launch_bounds__(64) void conv_pass2(
    const float* __restrict__ z,
    const float* __restrict__ wr_,
    const float* __restrict__ wi_,
    const float* __restrict__ cr_,
    const float* __restrict__ ci_,
    const float* __restrict__ bend_r,
    const float* __restrict__ bend_i,
    const float* __restrict__ D_skip,
    ushort* __restrict__ yb)
{
    __shared__ float zs[2][TCH];
    __shared__ float ys[2][TCH];
    const int half = threadIdx.x >> 5;
    const int lane = threadIdx.x & 31;
    const int h = blockIdx.x * 2 + half;
    const int hh = (h < H) ? h : (H - 1);
    const int c = blockIdx.y;

    const float* zrow = z + (size_t)hh * L + c * TCH;
    for (int i = lane; i < TCH; i += 32) zs[half][i] = zrow[i];

    const int cidx = hh * NST + lane;
    const float wr = wr_[cidx], wi = wi_[cidx];
    const float cr = cr_[cidx], ci = ci_[cidx];
    const float Dh = D_skip[hh];
    float sr = bend_r[(size_t)c * HN + cidx];
    float si = bend_i[(size_t)c * HN + cidx];
    __syncthreads();

    for (int l = 0; l < TCH; ++l) {
        float zl = zs[half][l];
        float nsr = fmaf(wr, sr, fmaf(-wi, si, zl));
        float nsi = fmaf(wr, si, wi * sr);
        sr = nsr; si = nsi;
        float p = fmaf(cr, sr, -ci * si);
        p = reduce32_to_lane31(p);
        if (lane == 31) ys[half][l] = fmaf(Dh, zl, p);
    }
    __syncthreads();

    if (h < H) {
        ushort* yrow = yb + (size_t)h * L + c * TCH;
        for (int i = lane; i < TCH; i += 32) yrow[i] = f2bf(gelu_tanh(ys[half][i]));
    }
}

// ---------------------------------------------------------------------------
// Transpose y bf16 (H,L) -> ytb bf16 (L,HP), zero-filling h=511.
// ---------------------------------------------------------------------------
__global__ __launch_bounds__(256) void ytr_kernel(
    const ushort* __restrict__ yb,
    ushort* __restrict__ ytb)
{
    __shared__ ushort t[32][34];
    const int tx = threadIdx.x;      // 0..31
    const int ty = threadIdx.y;      // 0..7
    const int l0 = blockIdx.x * 32;
    const int h0 = blockIdx.y * 32;
    #pragma unroll
    for (int j = 0; j < 4; ++j) {
        int h = h0 + ty + j * 8;
        ushort v = 0;
        if (h < H) v = yb[(size_t)h * L + l0 + tx];
        t[tx][ty + j * 8] = v;       // t[l_local][h_local]
    }
    __syncthreads();
    #pragma unroll
    for (int j = 0; j < 4; ++j) {
        int l = l0 + ty + j * 8;
        ytb[(size_t)l * HP + h0 + tx] = t[ty + j * 8][tx];
    }
}

// ---------------------------------------------------------------------------
// MFMA GLU GEMM: C = wbf (2H,HP) . ytb^T (HP,L); GLU over gate pairs +
// residual. Block: 32 gate-paired rows x 64 cols, 4 waves (2x2), BK=64,
// XOR-swizzled LDS (kgrp ^= row&7) on write AND read -> conflict-free.
// ---------------------------------------------------------------------------
__global__ __launch_bounds__(256) void glu_mfma(
    const ushort* __restrict__ wbf,   // (2H, HP) bf16
    const ushort* __restrict__ ytb,   // (L, HP) bf16
    const float* __restrict__ bias,   // (2H)
    const float* __restrict__ zres,   // (H,L)
    float* __restrict__ out)          // (H,L)
{
    __shared__ ushort As1[32 * GBK];
    __shared__ ushort As2[32 * GBK];
    __shared__ ushort Bs[GBN * GBK];

    const int tid = threadIdx.x;
    const int h0 = blockIdx.y * 32;
    const int l0 = blockIdx.x * GBN;
    const int wid = tid >> 6;
    const int lane = tid & 63;
    const int wrow = (wid >> 1) * 16;    // 0 or 16
    const int wcol = (wid & 1) * 32;     // 0 or 32

    f32x4 acc1[2] = {{0.f,0.f,0.f,0.f},{0.f,0.f,0.f,0.f}};
    f32x4 acc2[2] = {{0.f,0.f,0.f,0.f},{0.f,0.f,0.f,0.f}};

    // staging indices: thread -> (row 0..31, kgrp 0..7)
    const int ar = tid >> 3;
    const int ak = tid & 7;
    const int hq1 = (h0 + ar < H) ? (h0 + ar) : (H - 1);   // clamp; tail rows discarded at store
    const int hq2 = hq1 + H;
    const int aswz = ak ^ (ar & 7);

    for (int k0 = 0; k0 < HP; k0 += GBK) {
        short8 va1 = *(const short8*)&wbf[(size_t)hq1 * HP + k0 + ak * 8];
        short8 va2 = *(const short8*)&wbf[(size_t)hq2 * HP + k0 + ak * 8];
        *(short8*)&As1[ar * GBK + aswz * 8] = va1;
        *(short8*)&As2[ar * GBK + aswz * 8] = va2;
        #pragma unroll
        for (int j = 0; j < 2; ++j) {
            int idx = tid + j * 256;
            int br = idx >> 3;       // l-local 0..63
            int bk = idx & 7;
            short8 vb = *(const short8*)&ytb[(size_t)(l0 + br) * HP + k0 + bk * 8];
            *(short8*)&Bs[br * GBK + (bk ^ (br & 7)) * 8] = vb;
        }
        __syncthreads();

        #pragma unroll
        for (int kk = 0; kk < 2; ++kk) {
            const int arow = wrow + (lane & 15);
            const int kg = kk * 4 + (lane >> 4);
            short8 a1 = *(const short8*)&As1[arow * GBK + (kg ^ (arow & 7)) * 8];
            short8 a2 = *(const short8*)&As2[arow * GBK + (kg ^ (arow & 7)) * 8];
            #pragma unroll
            for (int nf = 0; nf < 2; ++nf) {
                const int brow = wcol + nf * 16 + (lane & 15);
                short8 b = *(const short8*)&Bs[brow * GBK + (kg ^ (brow & 7)) * 8];
                acc1[nf] = __builtin_amdgcn_mfma_f32_16x16x32_bf16(a1, b, acc1[nf], 0, 0, 0);
                acc2[nf] = __builtin_amdgcn_mfma_f32_16x16x32_bf16(a2, b, acc2[nf], 0, 0, 0);
            }
        }
        __syncthreads();
    }

    // epilogue: C/D layout col=lane&15, row=(lane>>4)*4+reg  [m89-verified]
    #pragma unroll
    for (int nf = 0; nf < 2; ++nf) {
        const int col = l0 + wcol + nf * 16 + (lane & 15);
        #pragma unroll
        for (int r = 0; r < 4; ++r) {
            const int h = h0 + wrow + (lane >> 4) * 4 + r;
            if (h < H) {
                float v1 = acc1[nf][r] + bias[h];
                float v2 = acc2[nf][r] + bias[h + H];
                float g = v1 * (1.0f / (1.0f + expf(-v2)));
                out[(size_t)h * L + col] = g + zres[(size_t)h * L + col];
            }
        }
    }
}

// ---------------------------------------------------------------------------
// LN phase 1: per-stripe partial sums. Grid (L/64, NSTRIPE); block 64x4.
// Stripe s covers h in [s*32, s*32+32) (clipped to H).
// ---------------------------------------------------------------------------
__global__ __launch_bounds__(256) void ln_stats(
    const float* __restrict__ zpre,
    float* __restrict__ psum, float* __restrict__ psq)
{
    __shared__ float ss[4][64];
    __shared__ float sg[4][64];
    const int tx = threadIdx.x & 63;
    const int ty = threadIdx.x >> 6;
    const int l = blockIdx.x * 64 + tx;
    const int s = blockIdx.y;
    const int hbase = s * 32;

    float sum = 0.f, sq = 0.f;
    #pragma unroll
    for (int j = 0; j < 8; ++j) {
        int h = hbase + ty + j * 4;
        if (h < H) {
            float v = zpre[(size_t)h * L + l];
            sum += v;
            sq = fmaf(v, v, sq);
        }
    }
    ss[ty][tx] = sum;
    sg[ty][tx] = sq;
    __syncthreads();
    if (ty == 0) {
        psum[(size_t)s * L + l] = ss[0][tx] + ss[1][tx] + ss[2][tx] + ss[3][tx];
        psq[(size_t)s * L + l]  = sg[0][tx] + sg[1][tx] + sg[2][tx] + sg[3][tx];
    }
}

// ---------------------------------------------------------------------------
// LN phase 2: fold partials -> mu/rstd per column; apply over this stripe.
// ---------------------------------------------------------------------------
__global__ __launch_bounds__(256) void ln_apply(
    const float* __restrict__ zpre,
    const float* __restrict__ psum, const float* __restrict__ psq,
    const float* __restrict__ g, const float* __restrict__ b,
    float* __restrict__ out)
{
    const int tx = threadIdx.x & 63;
    const int ty = threadIdx.x >> 6;
    const int l = blockIdx.x * 64 + tx;
    const int s = blockIdx.y;

    float S = 0.f, Q = 0.f;
    #pragma unroll
    for (int k = 0; k < NSTRIPE; ++k) {
        S += psum[(size_t)k * L + l];
        Q += psq[(size_t)k * L + l];
    }
    const float invH = 1.0f / (float)H;
    float mu = S * invH;
    float var = Q * invH - mu * mu;
    float rstd = rsqrtf(var + LN_EPS);

    const int hbase = s * 32;
    #pragma unroll
    for (int j = 0; j < 8; ++j) {
        int h = hbase + ty + j * 4;
        if (h < H) {
            float v = zpre[(size_t)h * L + l];
            out[(size_t)h * L + l] = (v - mu) * rstd * g[h] + b[h];
        }
    }
}

// ---------------------------------------------------------------------------
extern "C" void kernel_launch(void* const* d_in, const int* in_sizes, int n_in,
                              void* d_out, int out_size, void* d_ws, size_t ws_size,
                              hipStream_t stream) {
    const float* Z          = (const float*)d_in[0];
    const float* log_dt     = (const float*)d_in[1];
    const float* A_real_log = (const float*)d_in[2];
    const float* A_imag     = (const float*)d_in[3];
    const float* C_re       = (const float*)d_in[4];
    const float* C_im       = (const float*)d_in[5];
    const float* D_skip     = (const float*)d_in[6];
    const float* glu_w      = (const float*)d_in[7];
    const float* glu_b      = (const float*)d_in[8];
    const float* ln_g       = (const float*)d_in[9];
    const float* ln_b       = (const float*)d_in[10];

    float* out = (float*)d_out;
    float* ws  = (float*)d_ws;

    // fp32 regions (all multiples of 16 floats -> 16B-aligned)
    float* wr     = ws;
    float* wi     = wr + HN;
    float* cr     = wi + HN;
    float* ci     = cr + HN;
    float* zbuf   = ci + HN;                          // (H,L) fp32
    float* bend_r = zbuf + (size_t)H * L;             // (NCHUNK,HN)
    float* bend_i = bend_r + (size_t)NCHUNK * HN;
    float* psum   = bend_i + (size_t)NCHUNK * HN;     // (NSTRIPE,L)
    float* psq    = psum + (size_t)NSTRIPE * L;
    // bf16 regions
    ushort* yb  = (ushort*)(psq + (size_t)NSTRIPE * L);     // (H,L) bf16
    ushort* ytb = yb + (size_t)H * L;                        // (L,HP) bf16
    ushort* wbf = ytb + (size_t)L * HP;                      // (2H,HP) bf16

    precompute_coef<<<(HN + 255) / 256, 256, 0, stream>>>(
        log_dt, A_real_log, A_imag, C_re, C_im, wr, wi, cr, ci);
    w_to_bf16<<<(2 * H * HP + 255) / 256, 256, 0, stream>>>(glu_w, wbf);

    const dim3 cg((H + 1) / 2, NCHUNK);
    const dim3 tg(L / 32, HP / 32);
    const dim3 tb(32, 8);
    const dim3 gg(L / GBN, (H + 31) / 32);
    const dim3 lg(L / 64, NSTRIPE);

    for (int layer = 0; layer < NLAYERS; ++layer) {
        const float* zcur = (layer == 0) ? Z : zbuf;

        conv_pass1<<<cg, 64, 0, stream>>>(zcur, wr, wi, bend_r, bend_i);
        conv_combine<<<(HN + 255) / 256, 256, 0, stream>>>(wr, wi, bend_r, bend_i);
        conv_pass2<<<cg, 64, 0, stream>>>(zcur, wr, wi, cr, ci,
                                          bend_r, bend_i, D_skip, yb);
        ytr_kernel<<<tg, tb, 0, stream>>>(yb, ytb);
        glu_mfma<<<gg, 256, 0, stream>>>(wbf, ytb, glu_b, zcur, out);

        float* lnout = (layer < NLAYERS - 1) ? zbuf : out;
        ln_stats<<<lg, 256, 0, stream>>>(out, psum, psq);
        ln_apply<<<lg, 256, 0, stream>>>(out, psum, psq, ln_g, ln_b, lnout);
    }
}